// Round 2
// baseline (554.521 us; speedup 1.0000x reference)
//
#include <hip/hip_runtime.h>
#include <stdint.h>
#include <stddef.h>

// ---------- problem constants ----------
constexpr int BATCH = 2;
constexpr int SEQ   = 2048;
constexpr int EMB   = 2048;   // DIM
constexpr int HEADS = 16;
constexpr int GQA   = 4;      // kv heads
constexpr int HDIM  = 128;
constexpr int NQKV  = 3072;   // 2048 Q + 512 K + 512 V
constexpr int VOFF  = 2560;   // column offset of V region in fused QKV
constexpr int MROWS = BATCH * SEQ;  // 4096
constexpr int VROWS = 144;    // Vt rows per (b,g): 128 data + ones row(128) + 15 zero

typedef _Float16 half8  __attribute__((ext_vector_type(8)));
typedef _Float16 half4v __attribute__((ext_vector_type(4)));
typedef float    floatx4 __attribute__((ext_vector_type(4)));

__device__ __forceinline__ void st_c(float* p, float v)    { *p = v; }
__device__ __forceinline__ void st_c(_Float16* p, float v) { *p = (_Float16)v; }

// ---------- 1. cast x (fp32 -> f16) ----------
__global__ void cast_x_kernel(const float* __restrict__ x, _Float16* __restrict__ xh) {
    int i = (blockIdx.x * 256 + threadIdx.x) * 4;
    float4 v = *(const float4*)(x + i);
    half4v h;
    h[0] = (_Float16)v.x; h[1] = (_Float16)v.y; h[2] = (_Float16)v.z; h[3] = (_Float16)v.w;
    *(half4v*)(xh + i) = h;
}

// ---------- 2. transpose + cast: out[C x R] = in[R x C]^T ----------
__global__ void transpose_cast(const float* __restrict__ in, _Float16* __restrict__ out,
                               int R, int C) {
    __shared__ float tile[32][33];
    int cb = blockIdx.x * 32, rb = blockIdx.y * 32;
    int tx = threadIdx.x, ty = threadIdx.y;    // 32 x 8
    #pragma unroll
    for (int j = 0; j < 32; j += 8)
        tile[ty + j][tx] = in[(size_t)(rb + ty + j) * C + (cb + tx)];
    __syncthreads();
    #pragma unroll
    for (int j = 0; j < 32; j += 8)
        out[(size_t)(cb + ty + j) * R + (rb + tx)] = (_Float16)tile[tx][ty + j];
}

// ---------- 3. GEMM: C[M,N] = A[M,K] * Bt[N,K]^T  (f16 in, fp32 acc) ----------
template <typename CT>
__global__ __launch_bounds__(256) void gemm_bt(const _Float16* __restrict__ A,
                                               const _Float16* __restrict__ Bt,
                                               CT* __restrict__ C,
                                               int M, int N, int K) {
    constexpr int LDT = 40;
    __shared__ _Float16 As[128 * LDT];
    __shared__ _Float16 Bs[128 * LDT];
    const int tid  = threadIdx.x;
    const int bm   = blockIdx.y * 128, bn = blockIdx.x * 128;
    const int lane = tid & 63, wid = tid >> 6;
    const int wr   = wid >> 1, wc = wid & 1;
    const int qd   = lane >> 4, m15 = lane & 15;

    const int sr = tid >> 2;
    const int sc = (tid & 3) * 8;
    const _Float16* Ag  = A  + (size_t)(bm + sr) * K + sc;
    const _Float16* Ag2 = Ag + (size_t)64 * K;
    const _Float16* Bg  = Bt + (size_t)(bn + sr) * K + sc;
    const _Float16* Bg2 = Bg + (size_t)64 * K;

    half8 a0 = *(const half8*)(Ag);
    half8 a1 = *(const half8*)(Ag2);
    half8 b0 = *(const half8*)(Bg);
    half8 b1 = *(const half8*)(Bg2);

    floatx4 acc[4][4] = {};

    _Float16* AsW  = As + sr * LDT + sc;
    _Float16* AsW2 = AsW + 64 * LDT;
    _Float16* BsW  = Bs + sr * LDT + sc;
    _Float16* BsW2 = BsW + 64 * LDT;
    const _Float16* AsR = As + (wr * 64 + m15) * LDT + qd * 8;
    const _Float16* BsR = Bs + (wc * 64 + m15) * LDT + qd * 8;

    for (int k0 = 0; k0 < K; k0 += 32) {
        *(half8*)AsW  = a0;  *(half8*)AsW2 = a1;
        *(half8*)BsW  = b0;  *(half8*)BsW2 = b1;
        __syncthreads();
        if (k0 + 32 < K) {
            a0 = *(const half8*)(Ag  + k0 + 32);
            a1 = *(const half8*)(Ag2 + k0 + 32);
            b0 = *(const half8*)(Bg  + k0 + 32);
            b1 = *(const half8*)(Bg2 + k0 + 32);
        }
        half8 af[4], bf[4];
        #pragma unroll
        for (int i = 0; i < 4; i++) af[i] = *(const half8*)(AsR + i * 16 * LDT);
        #pragma unroll
        for (int i = 0; i < 4; i++) bf[i] = *(const half8*)(BsR + i * 16 * LDT);
        #pragma unroll
        for (int mi = 0; mi < 4; mi++)
            #pragma unroll
            for (int ni = 0; ni < 4; ni++)
                acc[mi][ni] = __builtin_amdgcn_mfma_f32_16x16x32_f16(af[mi], bf[ni], acc[mi][ni], 0, 0, 0);
        __syncthreads();
    }

    #pragma unroll
    for (int mi = 0; mi < 4; mi++)
        #pragma unroll
        for (int ni = 0; ni < 4; ni++)
            #pragma unroll
            for (int r = 0; r < 4; r++) {
                int row = bm + wr * 64 + mi * 16 + qd * 4 + r;
                int col = bn + wc * 64 + ni * 16 + m15;
                st_c(&C[(size_t)row * N + col], acc[mi][ni][r]);
            }
}

// ---------- 4a. RoPE in-place on Q and K regions of fused QKV ----------
__global__ void rope_inplace(_Float16* __restrict__ qkv, const float* __restrict__ fc,
                             const float* __restrict__ fs) {
    int t   = blockIdx.x * 256 + threadIdx.x;
    int row = t / 1280;
    int p   = t - row * 1280;
    int s   = row & (SEQ - 1);
    int col, i;
    if (p < 1024) { col = 2 * p;                 i = p & 63; }
    else          { col = EMB + 2 * (p - 1024);  i = (p - 1024) & 63; }
    float c  = fc[s * 64 + i];
    float sn = fs[s * 64 + i];
    _Float16* ptr = qkv + (size_t)row * NQKV + col;
    float xr = (float)ptr[0], xi = (float)ptr[1];
    ptr[0] = (_Float16)(xr * c - xi * sn);
    ptr[1] = (_Float16)(xr * sn + xi * c);
}

// ---------- 4b. V -> Vt[b][g][d][s]  (d rows 0..127) ----------
__global__ void transpose_v(const _Float16* __restrict__ qkv, _Float16* __restrict__ vt) {
    __shared__ _Float16 tile[32][33];
    int sb = blockIdx.x * 32, db = blockIdx.y * 32;
    int bg = blockIdx.z;
    int tx = threadIdx.x, ty = threadIdx.y;
    const _Float16* src = qkv + (size_t)(bg >> 2) * SEQ * NQKV + VOFF + (bg & 3) * HDIM;
    #pragma unroll
    for (int j = 0; j < 32; j += 8)
        tile[ty + j][tx] = src[(size_t)(sb + ty + j) * NQKV + db + tx];
    __syncthreads();
    _Float16* dst = vt + (size_t)bg * VROWS * SEQ;
    #pragma unroll
    for (int j = 0; j < 32; j += 8)
        dst[(size_t)(db + ty + j) * SEQ + sb + tx] = tile[tx][ty + j];
}

// ---------- 4c. init Vt rows 128..143: row 128 = ones (row-sum trick), rest 0 ----------
__global__ void vt_ones_init(_Float16* __restrict__ vt) {
    int idx = blockIdx.x * 256 + threadIdx.x;        // 0 .. 16*SEQ-1
    int bg  = blockIdx.y;
    int d   = 128 + (idx >> 11);
    int col = idx & (SEQ - 1);
    vt[(size_t)bg * VROWS * SEQ + (size_t)d * SEQ + col] = (d == 128) ? (_Float16)1.0f : (_Float16)0.0f;
}

// ---------- 5. flash attention: barrier-free, one independent wave per 16 q-rows ----------
// Each wave owns q-subtile s (16 rows), loops over all causal 64-key tiles.
// K/V fragments load directly global -> VGPR in MFMA B-operand layout
// (B[n=lane&15][k=quad*8+j]); only the P C->A layout transform round-trips
// through a per-wave private LDS slice (in-order DS ops, no barrier needed).
// o[8] accumulates P @ ones-row => running l with automatic alpha rescale.
__global__ __launch_bounds__(256, 3) void flash_attn(const _Float16* __restrict__ qkv,
                                                     const _Float16* __restrict__ vt,
                                                     _Float16* __restrict__ ob) {
    const int i   = blockIdx.x;    // 0..31
    const int h   = blockIdx.y;
    const int b   = blockIdx.z;
    const int g   = h >> 2;
    const int tid = threadIdx.x;
    const int lane = tid & 63, wid = tid >> 6;
    const int qd = lane >> 4, m15 = lane & 15;

    __shared__ _Float16 Ps[4][16 * 72];   // per-wave private P slice

    // balanced subtile assignment: {i, 63-i, 64+i, 127-i} -> const work/block
    int s;
    if      (wid == 0) s = i;
    else if (wid == 1) s = 63 - i;
    else if (wid == 2) s = 64 + i;
    else               s = 127 - i;
    const int q0     = s * 16;
    const int ktLast = s >> 2;            // last 64-key tile index (diagonal)

    // Q fragments (A-operand: A[m=lane&15][k=qd*8+j])
    half8 qf[4];
    {
        const _Float16* qb = qkv + (size_t)(b * SEQ + q0 + m15) * NQKV + h * HDIM + qd * 8;
        #pragma unroll
        for (int kc = 0; kc < 4; kc++) qf[kc] = *(const half8*)(qb + kc * 32);
    }

    floatx4 o[9] = {};                    // o[0..7] = output dims, o[8] = row-sum (l)
    float mr[4];
    #pragma unroll
    for (int r = 0; r < 4; r++) mr[r] = -__builtin_inff();
    const float scale = 0.08838834764831845f;  // 1/sqrt(128)

    const _Float16* kg = qkv + (size_t)(b * SEQ) * NQKV + EMB + g * HDIM + qd * 8;
    const _Float16* vg = vt + (size_t)(b * GQA + g) * VROWS * SEQ + qd * 8;
    _Float16* pw = Ps[wid];

    for (int kt = 0; kt <= ktLast; ++kt) {
        const int k0 = kt * 64;

        // S = Q K^T : K fragments straight from global (L2-resident)
        floatx4 sa[4] = {};
        #pragma unroll
        for (int nt = 0; nt < 4; ++nt) {
            const _Float16* kr = kg + (size_t)(k0 + nt * 16 + m15) * NQKV;
            #pragma unroll
            for (int kc = 0; kc < 4; ++kc)
                sa[nt] = __builtin_amdgcn_mfma_f32_16x16x32_f16(qf[kc], *(const half8*)(kr + kc * 32), sa[nt], 0, 0, 0);
        }

        // scale + causal mask + running max
        const bool diag = (kt == ktLast);
        float mn[4], al[4];
        #pragma unroll
        for (int r = 0; r < 4; r++) {
            const int rowg = q0 + qd * 4 + r;
            #pragma unroll
            for (int nt = 0; nt < 4; nt++) {
                float v = sa[nt][r] * scale;
                if (diag && (k0 + nt * 16 + m15 > rowg)) v = -__builtin_inff();
                sa[nt][r] = v;
            }
            float mt = fmaxf(fmaxf(sa[0][r], sa[1][r]), fmaxf(sa[2][r], sa[3][r]));
            mt = fmaxf(mt, __shfl_xor(mt, 1, 64));
            mt = fmaxf(mt, __shfl_xor(mt, 2, 64));
            mt = fmaxf(mt, __shfl_xor(mt, 4, 64));
            mt = fmaxf(mt, __shfl_xor(mt, 8, 64));
            float mnew = fmaxf(mr[r], mt);
            al[r] = __expf(mr[r] - mnew);
            mn[r] = mnew; mr[r] = mnew;
        }

        // p = exp(s - m), store to private LDS slice; rescale all accumulators
        #pragma unroll
        for (int r = 0; r < 4; r++) {
            #pragma unroll
            for (int nt = 0; nt < 4; nt++) {
                float p = __expf(sa[nt][r] - mn[r]);
                pw[(qd * 4 + r) * 72 + nt * 16 + m15] = (_Float16)p;
            }
            #pragma unroll
            for (int dt = 0; dt < 9; dt++) o[dt][r] *= al[r];
        }

        // P fragments back (A-operand); V fragments straight from global
        half8 pf0 = *(const half8*)(&pw[m15 * 72 + qd * 8]);
        half8 pf1 = *(const half8*)(&pw[m15 * 72 + 32 + qd * 8]);
        #pragma unroll
        for (int dt = 0; dt < 9; dt++) {
            const _Float16* vr = vg + (size_t)(dt * 16 + m15) * SEQ + k0;
            o[dt] = __builtin_amdgcn_mfma_f32_16x16x32_f16(pf0, *(const half8*)(vr), o[dt], 0, 0, 0);
            o[dt] = __builtin_amdgcn_mfma_f32_16x16x32_f16(pf1, *(const half8*)(vr + 32), o[dt], 0, 0, 0);
        }
    }

    // epilogue: l lives in o[8][r] of lanes with m15==0; broadcast within quad
    float linv[4];
    #pragma unroll
    for (int r = 0; r < 4; r++) {
        float l = __shfl(o[8][r], lane & 48, 64);
        linv[r] = 1.0f / l;
    }
    _Float16* od = ob + (size_t)(b * SEQ + q0) * EMB + h * HDIM;
    #pragma unroll
    for (int dt = 0; dt < 8; dt++)
        #pragma unroll
        for (int r = 0; r < 4; r++)
            od[(size_t)(qd * 4 + r) * EMB + dt * 16 + m15] = (_Float16)(o[dt][r] * linv[r]);
}

// ---------- launcher ----------
extern "C" void kernel_launch(void* const* d_in, const int* in_sizes, int n_in,
                              void* d_out, int out_size, void* d_ws, size_t ws_size,
                              hipStream_t stream) {
    (void)in_sizes; (void)n_in; (void)out_size; (void)ws_size;
    const float* x  = (const float*)d_in[0];
    const float* fc = (const float*)d_in[1];
    const float* fs = (const float*)d_in[2];
    const float* Wq = (const float*)d_in[3];
    const float* Wk = (const float*)d_in[4];
    const float* Wv = (const float*)d_in[5];
    const float* Wo = (const float*)d_in[6];
    float* out = (float*)d_out;

    // workspace layout (f16), 60 MB:
    //  Xb   [ 0,16) MB   x cast; later reused as attention output Ob
    //  Wqkv [16,28) MB   fused W_qkv^T; dead after QKV GEMM -> reused for Vt (9 MB)
    //  WoT  [28,36) MB
    //  C1   [36,60) MB   fused QKV activations
    _Float16* Xb   = (_Float16*)d_ws;
    _Float16* Wqkv = Xb   + (size_t)MROWS * EMB;
    _Float16* WoT  = Wqkv + (size_t)NQKV * EMB;
    _Float16* C1   = WoT  + (size_t)EMB * EMB;
    _Float16* Vt   = Wqkv;                         // reuse (after QKV GEMM)
    _Float16* Ob   = Xb;                           // reuse (after QKV GEMM)

    dim3 tb(32, 8);
    cast_x_kernel<<<MROWS * EMB / 1024, 256, 0, stream>>>(x, Xb);
    transpose_cast<<<dim3(EMB / 32, EMB / 32), tb, 0, stream>>>(Wq, Wqkv, EMB, EMB);
    transpose_cast<<<dim3(512 / 32, EMB / 32), tb, 0, stream>>>(Wk, Wqkv + (size_t)EMB * EMB, EMB, 512);
    transpose_cast<<<dim3(512 / 32, EMB / 32), tb, 0, stream>>>(Wv, Wqkv + (size_t)VOFF * EMB, EMB, 512);
    transpose_cast<<<dim3(EMB / 32, EMB / 32), tb, 0, stream>>>(Wo, WoT, EMB, EMB);

    gemm_bt<_Float16><<<dim3(NQKV / 128, MROWS / 128), 256, 0, stream>>>(Xb, Wqkv, C1, MROWS, NQKV, EMB);
    rope_inplace<<<MROWS * 1280 / 256, 256, 0, stream>>>(C1, fc, fs);
    transpose_v<<<dim3(SEQ / 32, HDIM / 32, BATCH * GQA), tb, 0, stream>>>(C1, Vt);
    vt_ones_init<<<dim3(16 * SEQ / 256, BATCH * GQA), 256, 0, stream>>>(Vt);
    flash_attn<<<dim3(32, HEADS, BATCH), 256, 0, stream>>>(C1, Vt, Ob);
    gemm_bt<float><<<dim3(EMB / 128, MROWS / 128), 256, 0, stream>>>(Ob, WoT, out, MROWS, EMB, EMB);
}

// Round 3
// 373.884 us; speedup vs baseline: 1.4831x; 1.4831x over previous
//
#include <hip/hip_runtime.h>
#include <stdint.h>
#include <stddef.h>

// ---------- problem constants ----------
constexpr int BATCH = 2;
constexpr int SEQ   = 2048;
constexpr int EMB   = 2048;   // DIM
constexpr int HEADS = 16;
constexpr int GQA   = 4;      // kv heads
constexpr int HDIM  = 128;
constexpr int NQKV  = 3072;   // 2048 Q + 512 K + 512 V
constexpr int VOFF  = 2560;   // column offset of V region in fused QKV
constexpr int MROWS = BATCH * SEQ;  // 4096

typedef _Float16 half8  __attribute__((ext_vector_type(8)));
typedef _Float16 half4v __attribute__((ext_vector_type(4)));
typedef float    floatx4 __attribute__((ext_vector_type(4)));

__device__ __forceinline__ void st_c(float* p, float v)    { *p = v; }
__device__ __forceinline__ void st_c(_Float16* p, float v) { *p = (_Float16)v; }

// ---------- 1. cast x (fp32 -> f16) ----------
__global__ void cast_x_kernel(const float* __restrict__ x, _Float16* __restrict__ xh) {
    int i = (blockIdx.x * 256 + threadIdx.x) * 4;
    float4 v = *(const float4*)(x + i);
    half4v h;
    h[0] = (_Float16)v.x; h[1] = (_Float16)v.y; h[2] = (_Float16)v.z; h[3] = (_Float16)v.w;
    *(half4v*)(xh + i) = h;
}

// ---------- 2. transpose + cast: out[C x R] = in[R x C]^T ----------
__global__ void transpose_cast(const float* __restrict__ in, _Float16* __restrict__ out,
                               int R, int C) {
    __shared__ float tile[32][33];
    int cb = blockIdx.x * 32, rb = blockIdx.y * 32;
    int tx = threadIdx.x, ty = threadIdx.y;    // 32 x 8
    #pragma unroll
    for (int j = 0; j < 32; j += 8)
        tile[ty + j][tx] = in[(size_t)(rb + ty + j) * C + (cb + tx)];
    __syncthreads();
    #pragma unroll
    for (int j = 0; j < 32; j += 8)
        out[(size_t)(cb + ty + j) * R + (rb + tx)] = (_Float16)tile[tx][ty + j];
}

// ---------- 3. GEMM: C[M,N] = A[M,K] * Bt[N,K]^T  (f16 in, fp32 acc) ----------
template <typename CT>
__global__ __launch_bounds__(256) void gemm_bt(const _Float16* __restrict__ A,
                                               const _Float16* __restrict__ Bt,
                                               CT* __restrict__ C,
                                               int M, int N, int K) {
    constexpr int LDT = 40;
    __shared__ _Float16 As[128 * LDT];
    __shared__ _Float16 Bs[128 * LDT];
    const int tid  = threadIdx.x;
    const int bm   = blockIdx.y * 128, bn = blockIdx.x * 128;
    const int lane = tid & 63, wid = tid >> 6;
    const int wr   = wid >> 1, wc = wid & 1;
    const int qd   = lane >> 4, m15 = lane & 15;

    const int sr = tid >> 2;
    const int sc = (tid & 3) * 8;
    const _Float16* Ag  = A  + (size_t)(bm + sr) * K + sc;
    const _Float16* Ag2 = Ag + (size_t)64 * K;
    const _Float16* Bg  = Bt + (size_t)(bn + sr) * K + sc;
    const _Float16* Bg2 = Bg + (size_t)64 * K;

    half8 a0 = *(const half8*)(Ag);
    half8 a1 = *(const half8*)(Ag2);
    half8 b0 = *(const half8*)(Bg);
    half8 b1 = *(const half8*)(Bg2);

    floatx4 acc[4][4] = {};

    _Float16* AsW  = As + sr * LDT + sc;
    _Float16* AsW2 = AsW + 64 * LDT;
    _Float16* BsW  = Bs + sr * LDT + sc;
    _Float16* BsW2 = BsW + 64 * LDT;
    const _Float16* AsR = As + (wr * 64 + m15) * LDT + qd * 8;
    const _Float16* BsR = Bs + (wc * 64 + m15) * LDT + qd * 8;

    for (int k0 = 0; k0 < K; k0 += 32) {
        *(half8*)AsW  = a0;  *(half8*)AsW2 = a1;
        *(half8*)BsW  = b0;  *(half8*)BsW2 = b1;
        __syncthreads();
        if (k0 + 32 < K) {
            a0 = *(const half8*)(Ag  + k0 + 32);
            a1 = *(const half8*)(Ag2 + k0 + 32);
            b0 = *(const half8*)(Bg  + k0 + 32);
            b1 = *(const half8*)(Bg2 + k0 + 32);
        }
        half8 af[4], bf[4];
        #pragma unroll
        for (int i = 0; i < 4; i++) af[i] = *(const half8*)(AsR + i * 16 * LDT);
        #pragma unroll
        for (int i = 0; i < 4; i++) bf[i] = *(const half8*)(BsR + i * 16 * LDT);
        #pragma unroll
        for (int mi = 0; mi < 4; mi++)
            #pragma unroll
            for (int ni = 0; ni < 4; ni++)
                acc[mi][ni] = __builtin_amdgcn_mfma_f32_16x16x32_f16(af[mi], bf[ni], acc[mi][ni], 0, 0, 0);
        __syncthreads();
    }

    #pragma unroll
    for (int mi = 0; mi < 4; mi++)
        #pragma unroll
        for (int ni = 0; ni < 4; ni++)
            #pragma unroll
            for (int r = 0; r < 4; r++) {
                int row = bm + wr * 64 + mi * 16 + qd * 4 + r;
                int col = bn + wc * 64 + ni * 16 + m15;
                st_c(&C[(size_t)row * N + col], acc[mi][ni][r]);
            }
}

// ---------- 4a. RoPE in-place on Q and K regions of fused QKV ----------
__global__ void rope_inplace(_Float16* __restrict__ qkv, const float* __restrict__ fc,
                             const float* __restrict__ fs) {
    int t   = blockIdx.x * 256 + threadIdx.x;
    int row = t / 1280;
    int p   = t - row * 1280;
    int s   = row & (SEQ - 1);
    int col, i;
    if (p < 1024) { col = 2 * p;                 i = p & 63; }
    else          { col = EMB + 2 * (p - 1024);  i = (p - 1024) & 63; }
    float c  = fc[s * 64 + i];
    float sn = fs[s * 64 + i];
    _Float16* ptr = qkv + (size_t)row * NQKV + col;
    float xr = (float)ptr[0], xi = (float)ptr[1];
    ptr[0] = (_Float16)(xr * c - xi * sn);
    ptr[1] = (_Float16)(xr * sn + xi * c);
}

// ---------- 4b. V -> Vt[b][g][d][s]  (d rows 0..127) ----------
__global__ void transpose_v(const _Float16* __restrict__ qkv, _Float16* __restrict__ vt) {
    __shared__ _Float16 tile[32][33];
    int sb = blockIdx.x * 32, db = blockIdx.y * 32;
    int bg = blockIdx.z;
    int tx = threadIdx.x, ty = threadIdx.y;
    const _Float16* src = qkv + (size_t)(bg >> 2) * SEQ * NQKV + VOFF + (bg & 3) * HDIM;
    #pragma unroll
    for (int j = 0; j < 32; j += 8)
        tile[ty + j][tx] = src[(size_t)(sb + ty + j) * NQKV + db + tx];
    __syncthreads();
    _Float16* dst = vt + (size_t)bg * HDIM * SEQ;
    #pragma unroll
    for (int j = 0; j < 32; j += 8)
        dst[(size_t)(db + ty + j) * SEQ + sb + tx] = tile[tx][ty + j];
}

// ---------- 5. flash attention with GQA K/V sharing ----------
// Block = (b, kv-group g, 16-row q-tile). Its 4 waves = the 4 Q-heads of g.
// K/V tiles staged cooperatively (coalesced, register-double-buffered like
// gemm_bt) into LDS once per 64-key tile, consumed by all 4 heads.
// Vs rows 128..143 are a static ones/zero block: accumulator o[8] = P @ ones
// carries the softmax denominator with automatic alpha rescaling.
__global__ __launch_bounds__(256, 3) void flash_attn(const _Float16* __restrict__ qkv,
                                                     const _Float16* __restrict__ vt,
                                                     _Float16* __restrict__ ob) {
    const int sidx = 127 - blockIdx.x;   // longest q-tiles dispatch first
    const int g    = blockIdx.y;
    const int b    = blockIdx.z;
    const int tid  = threadIdx.x;
    const int lane = tid & 63, wid = tid >> 6;
    const int h    = g * 4 + wid;        // this wave's Q head
    const int qd   = lane >> 4, m15 = lane & 15;

    __shared__ _Float16 Ks[64 * 136];    // [key][d], stride 136 (68 dwords = 4*odd)
    __shared__ _Float16 Vs[144 * 72];    // [d][key], rows 128..143 static ones/zeros
    __shared__ _Float16 Ps[4][16 * 72];  // per-wave private P slice

    const int q0     = sidx * 16;
    const int ktLast = sidx >> 2;

    // static ones/zero rows of Vs (row 128 = 1, rows 129..143 = 0), once
    for (int idx = tid; idx < 16 * 72; idx += 256) {
        int rr = idx / 72, cc = idx - rr * 72;
        Vs[(128 + rr) * 72 + cc] = (rr == 0) ? (_Float16)1.0f : (_Float16)0.0f;
    }

    // Q fragments (A-operand: A[m=lane&15][k=qd*8+j])
    half8 qf[4];
    {
        const _Float16* qb = qkv + (size_t)(b * SEQ + q0 + m15) * NQKV + h * HDIM + qd * 8;
        #pragma unroll
        for (int kc = 0; kc < 4; kc++) qf[kc] = *(const half8*)(qb + kc * 32);
    }

    floatx4 o[9] = {};                   // o[0..7] output dims, o[8] row-sum l
    float mr[4];
    #pragma unroll
    for (int r = 0; r < 4; r++) mr[r] = -__builtin_inff();
    const float scale = 0.08838834764831845f;  // 1/sqrt(128)

    const _Float16* kg = qkv + (size_t)(b * SEQ) * NQKV + EMB + g * HDIM;  // K region base
    const _Float16* vg = vt + (size_t)(b * GQA + g) * HDIM * SEQ;          // Vt base
    _Float16* pw = Ps[wid];

    // coalesced staging addresses: K 64x128 (16 thr/row), V 128x64 (8 thr/row)
    const int kr0 = tid >> 4, kcc = (tid & 15) * 8;
    const int vr0 = tid >> 3, vcc = (tid & 7) * 8;

    // prefetch tile kt=0 into registers
    half8 kreg[4], vreg[4];
    #pragma unroll
    for (int it = 0; it < 4; ++it)
        kreg[it] = *(const half8*)(kg + (size_t)(kr0 + it * 16) * NQKV + kcc);
    #pragma unroll
    for (int it = 0; it < 4; ++it)
        vreg[it] = *(const half8*)(vg + (size_t)(vr0 + it * 32) * SEQ + vcc);

    for (int kt = 0; kt <= ktLast; ++kt) {
        const int k0 = kt * 64;
        __syncthreads();   // previous iteration's LDS reads complete (also orders Vs ones-init)
        #pragma unroll
        for (int it = 0; it < 4; ++it)
            *(half8*)(&Ks[(kr0 + it * 16) * 136 + kcc]) = kreg[it];
        #pragma unroll
        for (int it = 0; it < 4; ++it)
            *(half8*)(&Vs[(vr0 + it * 32) * 72 + vcc]) = vreg[it];
        __syncthreads();   // staged

        if (kt < ktLast) {  // prefetch next tile, in flight across compute
            const int k0n = k0 + 64;
            #pragma unroll
            for (int it = 0; it < 4; ++it)
                kreg[it] = *(const half8*)(kg + (size_t)(k0n + kr0 + it * 16) * NQKV + kcc);
            #pragma unroll
            for (int it = 0; it < 4; ++it)
                vreg[it] = *(const half8*)(vg + (size_t)(vr0 + it * 32) * SEQ + k0n + vcc);
        }

        // S = Q K^T from LDS
        floatx4 sa[4] = {};
        #pragma unroll
        for (int nt = 0; nt < 4; ++nt)
            #pragma unroll
            for (int kc = 0; kc < 4; ++kc) {
                half8 kf = *(const half8*)(&Ks[(nt * 16 + m15) * 136 + kc * 32 + qd * 8]);
                sa[nt] = __builtin_amdgcn_mfma_f32_16x16x32_f16(qf[kc], kf, sa[nt], 0, 0, 0);
            }

        // scale + causal mask + running max
        const bool diag = (kt == ktLast);
        float mn[4], al[4];
        #pragma unroll
        for (int r = 0; r < 4; r++) {
            const int rowg = q0 + qd * 4 + r;
            #pragma unroll
            for (int nt = 0; nt < 4; nt++) {
                float v = sa[nt][r] * scale;
                if (diag && (k0 + nt * 16 + m15 > rowg)) v = -__builtin_inff();
                sa[nt][r] = v;
            }
            float mt = fmaxf(fmaxf(sa[0][r], sa[1][r]), fmaxf(sa[2][r], sa[3][r]));
            mt = fmaxf(mt, __shfl_xor(mt, 1, 64));
            mt = fmaxf(mt, __shfl_xor(mt, 2, 64));
            mt = fmaxf(mt, __shfl_xor(mt, 4, 64));
            mt = fmaxf(mt, __shfl_xor(mt, 8, 64));
            float mnew = fmaxf(mr[r], mt);
            al[r] = __expf(mr[r] - mnew);
            mn[r] = mnew; mr[r] = mnew;
        }

        // p = exp(s-m) -> private LDS slice; rescale accumulators
        #pragma unroll
        for (int r = 0; r < 4; r++) {
            #pragma unroll
            for (int nt = 0; nt < 4; nt++) {
                float p = __expf(sa[nt][r] - mn[r]);
                pw[(qd * 4 + r) * 72 + nt * 16 + m15] = (_Float16)p;
            }
            #pragma unroll
            for (int dt = 0; dt < 9; dt++) o[dt][r] *= al[r];
        }

        // P back as A-operand (wave-private, in-order DS); V fragments from LDS
        half8 pf0 = *(const half8*)(&pw[m15 * 72 + qd * 8]);
        half8 pf1 = *(const half8*)(&pw[m15 * 72 + 32 + qd * 8]);
        #pragma unroll
        for (int dt = 0; dt < 9; dt++) {
            half8 vf0 = *(const half8*)(&Vs[(dt * 16 + m15) * 72 + qd * 8]);
            half8 vf1 = *(const half8*)(&Vs[(dt * 16 + m15) * 72 + 32 + qd * 8]);
            o[dt] = __builtin_amdgcn_mfma_f32_16x16x32_f16(pf0, vf0, o[dt], 0, 0, 0);
            o[dt] = __builtin_amdgcn_mfma_f32_16x16x32_f16(pf1, vf1, o[dt], 0, 0, 0);
        }
    }

    // epilogue: l lives in o[8][r] of lanes with m15==0; broadcast within quad
    float linv[4];
    #pragma unroll
    for (int r = 0; r < 4; r++) {
        float l = __shfl(o[8][r], lane & 48, 64);
        linv[r] = 1.0f / l;
    }
    _Float16* od = ob + (size_t)(b * SEQ + q0) * EMB + h * HDIM;
    #pragma unroll
    for (int dt = 0; dt < 8; dt++)
        #pragma unroll
        for (int r = 0; r < 4; r++)
            od[(size_t)(qd * 4 + r) * EMB + dt * 16 + m15] = (_Float16)(o[dt][r] * linv[r]);
}

// ---------- launcher ----------
extern "C" void kernel_launch(void* const* d_in, const int* in_sizes, int n_in,
                              void* d_out, int out_size, void* d_ws, size_t ws_size,
                              hipStream_t stream) {
    (void)in_sizes; (void)n_in; (void)out_size; (void)ws_size;
    const float* x  = (const float*)d_in[0];
    const float* fc = (const float*)d_in[1];
    const float* fs = (const float*)d_in[2];
    const float* Wq = (const float*)d_in[3];
    const float* Wk = (const float*)d_in[4];
    const float* Wv = (const float*)d_in[5];
    const float* Wo = (const float*)d_in[6];
    float* out = (float*)d_out;

    // workspace layout (f16), 60 MB:
    //  Xb   [ 0,16) MB   x cast; later reused as attention output Ob
    //  Wqkv [16,28) MB   fused W_qkv^T; dead after QKV GEMM -> reused for Vt (4 MB)
    //  WoT  [28,36) MB
    //  C1   [36,60) MB   fused QKV activations
    _Float16* Xb   = (_Float16*)d_ws;
    _Float16* Wqkv = Xb   + (size_t)MROWS * EMB;
    _Float16* WoT  = Wqkv + (size_t)NQKV * EMB;
    _Float16* C1   = WoT  + (size_t)EMB * EMB;
    _Float16* Vt   = Wqkv;                         // reuse (after QKV GEMM)
    _Float16* Ob   = Xb;                           // reuse (after QKV GEMM)

    dim3 tb(32, 8);
    cast_x_kernel<<<MROWS * EMB / 1024, 256, 0, stream>>>(x, Xb);
    transpose_cast<<<dim3(EMB / 32, EMB / 32), tb, 0, stream>>>(Wq, Wqkv, EMB, EMB);
    transpose_cast<<<dim3(512 / 32, EMB / 32), tb, 0, stream>>>(Wk, Wqkv + (size_t)EMB * EMB, EMB, 512);
    transpose_cast<<<dim3(512 / 32, EMB / 32), tb, 0, stream>>>(Wv, Wqkv + (size_t)VOFF * EMB, EMB, 512);
    transpose_cast<<<dim3(EMB / 32, EMB / 32), tb, 0, stream>>>(Wo, WoT, EMB, EMB);

    gemm_bt<_Float16><<<dim3(NQKV / 128, MROWS / 128), 256, 0, stream>>>(Xb, Wqkv, C1, MROWS, NQKV, EMB);
    rope_inplace<<<MROWS * 1280 / 256, 256, 0, stream>>>(C1, fc, fs);
    transpose_v<<<dim3(SEQ / 32, HDIM / 32, BATCH * GQA), tb, 0, stream>>>(C1, Vt);
    flash_attn<<<dim3(128, GQA, BATCH), 256, 0, stream>>>(C1, Vt, Ob);
    gemm_bt<float><<<dim3(EMB / 128, MROWS / 128), 256, 0, stream>>>(Ob, WoT, out, MROWS, EMB, EMB);
}